// Round 1
// baseline (885.326 us; speedup 1.0000x reference)
//
#include <hip/hip_runtime.h>
#include <math.h>

// SimpleBICEPLayer fused kernel.
//
// Reference math:
//   fb[b]        = sigmoid(x[b,:] . W_fb[0,:] + b_fb)
//   e[s]         = exp(-0.1 * s * dt),  dt = 1/50
//   endpoints[b,p] = sqrt(dt) * ( 0.5 * sum_s noise[b,p,s]
//                                + fb[b] * sum_s e[s]*noise[b,p,s] )
//   out[b,o]     = sum_p endpoints[b,p] * W_agg[o,p] + b_agg[o]
//
// Memory-bound: noise is 419 MB; floor ~75 us at 6.3 TB/s.

#define B_TOTAL 8192
#define D_IN    512
#define D_OUT   1024
#define NP      256
#define NS      50
#define BT      8      // batch rows per block
#define THREADS 256

#define SQRT_DT 0.14142135623730951f   // sqrt(1/50)
#define DECAY_DT 0.002f                // DECAY_RATE * dt

__device__ __forceinline__ float dot4acc(float4 e, float4 w, float a) {
    return fmaf(e.x, w.x, fmaf(e.y, w.y, fmaf(e.z, w.z, fmaf(e.w, w.w, a))));
}

__global__ __launch_bounds__(THREADS, 4) void bicep_fused(
    const float* __restrict__ x,
    const float* __restrict__ Wfb,
    const float* __restrict__ bfb,
    const float* __restrict__ Wagg,
    const float* __restrict__ bagg,
    const float* __restrict__ noise,
    float* __restrict__ out)
{
    __shared__ float fb_s[BT];
    __shared__ __align__(16) float E_s[NS + 2];     // e[s] table (+pad for float2)
    __shared__ __align__(16) float ep_s[BT * NP];   // endpoints tile, 8 KB

    const int tid  = threadIdx.x;
    const int b0   = blockIdx.x * BT;
    const int lane = tid & 63;
    const int wave = tid >> 6;

    // e[s] table (cheap, once per block)
    if (tid < NS) E_s[tid] = __expf(-DECAY_DT * (float)tid);

    // ---- Phase A: feedback sigmoid for BT rows (wave w -> rows 2w, 2w+1) ----
    {
        const float bf = bfb[0];
        const float4* wf = (const float4*)(Wfb + lane * 8);
        float4 wa = wf[0];
        float4 wb = wf[1];
        #pragma unroll
        for (int r2 = 0; r2 < 2; ++r2) {
            const int row = wave * 2 + r2;
            const float4* xr = (const float4*)(x + (size_t)(b0 + row) * D_IN + lane * 8);
            float4 xa = xr[0];
            float4 xb = xr[1];
            float p = dot4acc(xa, wa, 0.0f);
            p = dot4acc(xb, wb, p);
            #pragma unroll
            for (int m = 32; m >= 1; m >>= 1) p += __shfl_xor(p, m, 64);
            if (lane == 0) {
                float z = p + bf;
                fb_s[row] = 1.0f / (1.0f + __expf(-z));
            }
        }
    }
    __syncthreads();

    // ---- Phase B: endpoints. Thread owns 8 contiguous (b,p) pairs = 1600 B
    // of noise (per-lane sequential streaming: tiny L1 working set, full
    // cache-line utilization). ----
    {
        const int b_l = tid >> 5;            // 0..7
        const int p0  = (tid & 31) * 8;      // 0..248
        const float fbv = fb_s[b_l];
        const float2* nz = (const float2*)(noise + ((size_t)(b0 + b_l) * NP + p0) * NS);
        const float2* E2 = (const float2*)E_s;
        #pragma unroll 2
        for (int i = 0; i < 8; ++i) {
            float s0 = 0.0f, s1 = 0.0f;
            #pragma unroll
            for (int s2 = 0; s2 < NS / 2; ++s2) {
                float2 n2 = nz[i * (NS / 2) + s2];
                float2 e2 = E2[s2];                    // LDS broadcast
                s0 += n2.x + n2.y;
                s1 = fmaf(e2.x, n2.x, fmaf(e2.y, n2.y, s1));
            }
            ep_s[b_l * NP + p0 + i] = SQRT_DT * fmaf(fbv, s1, 0.5f * s0);
        }
    }
    __syncthreads();

    // ---- Phase C: out[b0..b0+7, :] = ep @ Wagg^T + bagg.
    // Thread owns 4 output columns (o4..o4+3) x all 8 rows.
    // Wagg rows read contiguously per lane (L2-resident); endpoints are
    // wave-uniform LDS broadcast b128 reads. ----
    {
        const int o4 = tid * 4;
        const float4 bg = *(const float4*)(bagg + o4);
        const float* w0p = Wagg + (size_t)(o4 + 0) * NP;
        const float* w1p = Wagg + (size_t)(o4 + 1) * NP;
        const float* w2p = Wagg + (size_t)(o4 + 2) * NP;
        const float* w3p = Wagg + (size_t)(o4 + 3) * NP;

        float acc[BT][4];
        #pragma unroll
        for (int b = 0; b < BT; ++b)
            #pragma unroll
            for (int q = 0; q < 4; ++q) acc[b][q] = 0.0f;

        for (int p = 0; p < NP; p += 4) {
            float4 w0 = *(const float4*)(w0p + p);
            float4 w1 = *(const float4*)(w1p + p);
            float4 w2 = *(const float4*)(w2p + p);
            float4 w3 = *(const float4*)(w3p + p);
            #pragma unroll
            for (int b = 0; b < BT; ++b) {
                float4 e4 = *(const float4*)&ep_s[b * NP + p];
                acc[b][0] = dot4acc(e4, w0, acc[b][0]);
                acc[b][1] = dot4acc(e4, w1, acc[b][1]);
                acc[b][2] = dot4acc(e4, w2, acc[b][2]);
                acc[b][3] = dot4acc(e4, w3, acc[b][3]);
            }
        }

        #pragma unroll
        for (int b = 0; b < BT; ++b) {
            float4 o = make_float4(acc[b][0] + bg.x, acc[b][1] + bg.y,
                                   acc[b][2] + bg.z, acc[b][3] + bg.w);
            *(float4*)(out + (size_t)(b0 + b) * D_OUT + o4) = o;
        }
    }
}

extern "C" void kernel_launch(void* const* d_in, const int* in_sizes, int n_in,
                              void* d_out, int out_size, void* d_ws, size_t ws_size,
                              hipStream_t stream) {
    const float* x     = (const float*)d_in[0];
    const float* Wfb   = (const float*)d_in[1];
    const float* bfb   = (const float*)d_in[2];
    const float* Wagg  = (const float*)d_in[3];
    const float* bagg  = (const float*)d_in[4];
    const float* noise = (const float*)d_in[5];
    float* out = (float*)d_out;

    dim3 grid(B_TOTAL / BT);
    dim3 block(THREADS);
    bicep_fused<<<grid, block, 0, stream>>>(x, Wfb, bfb, Wagg, bagg, noise, out);
}

// Round 3
// 668.606 us; speedup vs baseline: 1.3241x; 1.3241x over previous
//
#include <hip/hip_runtime.h>
#include <math.h>

// SimpleBICEPLayer fused kernel, round 3.
//
//   fb[b]          = sigmoid(x[b,:] . W_fb + b_fb)
//   endpoints[b,p] = sqrt(dt) * ( 0.5 * sum_s noise[b,p,s]
//                                + fb[b] * sum_s e[s]*noise[b,p,s] ),  e[s]=exp(-0.002 s)
//   out[b,o]       = sum_p endpoints[b,p] * W_agg[o,p] + b_agg[o]
//
// Memory-bound: noise 419 MB -> floor ~75 us at 6.3 TB/s.
// Round-3 change vs round-2: NO workspace use (round-2 wrote 512 KB to d_ws
// without checking ws_size -> corrupted neighboring allocations after the
// first call). Single kernel; the MFMA epilogue reads W_agg fp32 straight
// from global (L2-resident) in B-fragment order and converts to bf16
// in-register.

#define B_TOTAL 8192
#define D_IN    512
#define D_OUT   1024
#define NP      256
#define NS      50
#define BT      16
#define THREADS 256
#define PCHUNK  8
#define NCHUNK  (NP / PCHUNK)      // 32
#define CHUNK_F4 1600              // 16 rows * 8 p * 50 s / 4
#define ROW_F4   100               // per-row float4s per chunk (8*50/4)
#define EP_STRIDE 264              // 256 + 8 pad

#define SQRT_DT 0.14142135623730951f

typedef __bf16 bf16x8 __attribute__((ext_vector_type(8)));
typedef float  f32x4  __attribute__((ext_vector_type(4)));

__device__ __forceinline__ unsigned short f2bf(float f) {
    unsigned u = __float_as_uint(f);
    return (unsigned short)((u + 0x7FFFu + ((u >> 16) & 1u)) >> 16);
}

__global__ __launch_bounds__(THREADS, 2) void bicep_main(
    const float* __restrict__ x,
    const float* __restrict__ Wfb,
    const float* __restrict__ bfb,
    const float* __restrict__ Wagg,
    const float* __restrict__ bagg,
    const float* __restrict__ noise,
    float* __restrict__ out)
{
    __shared__ __align__(16) float nbuf[2][CHUNK_F4 * 4];          // 51200 B
    __shared__ __align__(16) unsigned short ep_bf[BT * EP_STRIDE]; // 8448 B
    __shared__ float fb_s[BT];
    __shared__ float bagg_s[D_OUT];                                // 4096 B

    const int tid  = threadIdx.x;
    const int lane = tid & 63;
    const int wave = tid >> 6;
    const int b0   = blockIdx.x * BT;

    // ---- Phase A: bias table, feedback sigmoid for 16 rows ----
    {
        #pragma unroll
        for (int i = 0; i < D_OUT / THREADS; ++i)
            bagg_s[i * THREADS + tid] = bagg[i * THREADS + tid];

        const float bf_b = bfb[0];
        const float4* wf = (const float4*)Wfb + lane * 2;
        float4 wa = wf[0], wb = wf[1];
        #pragma unroll
        for (int rr = 0; rr < 4; ++rr) {
            int row = wave * 4 + rr;
            const float4* xr = (const float4*)(x + (size_t)(b0 + row) * D_IN) + lane * 2;
            float4 xa = xr[0], xb = xr[1];
            float p = xa.x*wa.x + xa.y*wa.y + xa.z*wa.z + xa.w*wa.w
                    + xb.x*wb.x + xb.y*wb.y + xb.z*wb.z + xb.w*wb.w;
            #pragma unroll
            for (int mm = 32; mm >= 1; mm >>= 1) p += __shfl_xor(p, mm, 64);
            if (lane == 0) fb_s[row] = 1.0f / (1.0f + __expf(-(p + bf_b)));
        }
    }

    // ---- Per-thread constants for streaming + compute ----
    const int h     = tid & 1;          // s-half (0: s<25, 1: s>=25)
    const int jpair = tid >> 1;         // 0..127 pair within chunk
    const int c_row = jpair >> 3;       // 0..15  (wave-local: tid>>4)
    const int c_pl  = jpair & 7;        // 0..7

    float ereg[25];
    #pragma unroll
    for (int s = 0; s < 25; ++s)
        ereg[s] = __expf(-0.002f * (float)(h * 25 + s));

    // Staging map: flat float4 index g4 = r*256+tid over the 25.6 KB chunk;
    // row = g4/100, off = g4%100 (chunk c adds c*100 f4 within the row).
    const float4* nptr[7];
    #pragma unroll
    for (int r = 0; r < 7; ++r) {
        int g4  = r * 256 + tid;
        int row = g4 / 100;
        int off = g4 - row * 100;
        if (row > BT - 1) row = BT - 1;   // (r==6, tid>=64): never dereferenced
        nptr[r] = (const float4*)(noise + (size_t)(b0 + row) * (NP * NS)) + off;
    }

    float4 v[7];
    v[6] = make_float4(0.f, 0.f, 0.f, 0.f);
    #pragma unroll
    for (int r = 0; r < 6; ++r) v[r] = nptr[r][0];
    if (tid < 64) v[6] = nptr[6][0];

    // ---- Streaming loop: double-buffered LDS, 1 barrier per chunk ----
    for (int c = 0; c < NCHUNK; ++c) {
        float* nb = nbuf[c & 1];
        #pragma unroll
        for (int r = 0; r < 6; ++r) ((float4*)nb)[r * 256 + tid] = v[r];
        if (tid < 64) ((float4*)nb)[6 * 256 + tid] = v[6];

        if (c + 1 < NCHUNK) {            // prefetch next chunk
            #pragma unroll
            for (int r = 0; r < 6; ++r) v[r] = nptr[r][(c + 1) * ROW_F4];
            if (tid < 64) v[6] = nptr[6][(c + 1) * ROW_F4];
        }

        __syncthreads();

        // s-reduction: 2 threads per (row,p) pair, 25 floats each
        const float* src = &nb[c_row * (PCHUNK * NS) + c_pl * NS + h * 25];
        float s0 = 0.f, s1 = 0.f;
        #pragma unroll
        for (int s = 0; s < 25; ++s) {
            float nv = src[s];
            s0 += nv;
            s1 = fmaf(ereg[s], nv, s1);
        }
        s0 += __shfl_xor(s0, 1, 64);
        s1 += __shfl_xor(s1, 1, 64);
        if (h == 0) {
            float ep = SQRT_DT * fmaf(fb_s[c_row], s1, 0.5f * s0);
            ep_bf[c_row * EP_STRIDE + c * PCHUNK + c_pl] = f2bf(ep);
        }
    }
    __syncthreads();

    // ---- Epilogue: out[16 x 1024] = ep(16x256) @ W^T via bf16 MFMA.
    // A-frag: lane holds A[m=lane&15][k=(lane>>4)*8+j];
    // B-frag: lane holds B[k=(lane>>4)*8+j][n=lane&15] = W[O*16+n][k];
    // C/D:    col=lane&15, row=(lane>>4)*4+reg.
    // W_agg read fp32 from global (L2-resident), converted in-register. ----
    {
        const int m  = lane & 15;
        const int kg = lane >> 4;

        bf16x8 afr[8];
        #pragma unroll
        for (int ks = 0; ks < 8; ++ks)
            afr[ks] = *(const bf16x8*)&ep_bf[m * EP_STRIDE + ks * 32 + kg * 8];

        #pragma unroll 2
        for (int i = 0; i < 16; ++i) {
            int O = wave * 16 + i;               // o-tile: cols O*16..O*16+15
            const float* wp = Wagg + (size_t)(O * 16 + m) * NP + kg * 8;
            f32x4 acc = {0.f, 0.f, 0.f, 0.f};
            #pragma unroll
            for (int ks = 0; ks < 8; ++ks) {
                float4 wa = *(const float4*)(wp + ks * 32);
                float4 wb = *(const float4*)(wp + ks * 32 + 4);
                bf16x8 bfr = { (__bf16)wa.x, (__bf16)wa.y, (__bf16)wa.z, (__bf16)wa.w,
                               (__bf16)wb.x, (__bf16)wb.y, (__bf16)wb.z, (__bf16)wb.w };
                acc = __builtin_amdgcn_mfma_f32_16x16x32_bf16(afr[ks], bfr, acc, 0, 0, 0);
            }
            float bias = bagg_s[O * 16 + m];
            #pragma unroll
            for (int r = 0; r < 4; ++r)
                out[(size_t)(b0 + kg * 4 + r) * D_OUT + O * 16 + m] = acc[r] + bias;
        }
    }
}

extern "C" void kernel_launch(void* const* d_in, const int* in_sizes, int n_in,
                              void* d_out, int out_size, void* d_ws, size_t ws_size,
                              hipStream_t stream) {
    const float* x     = (const float*)d_in[0];
    const float* Wfb   = (const float*)d_in[1];
    const float* bfb   = (const float*)d_in[2];
    const float* Wagg  = (const float*)d_in[3];
    const float* bagg  = (const float*)d_in[4];
    const float* noise = (const float*)d_in[5];
    float* out = (float*)d_out;
    (void)d_ws; (void)ws_size;

    bicep_main<<<dim3(B_TOTAL / BT), dim3(THREADS), 0, stream>>>(
        x, Wfb, bfb, Wagg, bagg, noise, out);
}